// Round 4
// baseline (203.756 us; speedup 1.0000x reference)
//
#include <hip/hip_runtime.h>
#include <math.h>

#define Bsz 128
#define Usz 16
#define Dsz 256
#define Nsz 1024
#define Osz 256

typedef __attribute__((ext_vector_type(4))) float f32x4;
typedef __attribute__((ext_vector_type(8))) short bf16x8;

__device__ __forceinline__ unsigned short f2bf(float f) {
    union { float f; unsigned int u; } v; v.f = f;
    unsigned int lsb = (v.u >> 16) & 1u;
    v.u += 0x7fffu + lsb;   // RTE
    return (unsigned short)(v.u >> 16);
}

__device__ __forceinline__ bf16x8 pack8(const float* x, float s) {
    union { bf16x8 v; unsigned short h[8]; } r;
    #pragma unroll
    for (int i = 0; i < 8; i++) r.h[i] = f2bf(x[i] * s);
    return r.v;
}

// ---------------- lr = softmax_u(X·alr / T) ----------------
__global__ __launch_bounds__(256)
void lr_kernel(const float* __restrict__ X, const float* __restrict__ alr,
               const float* __restrict__ temp, float* __restrict__ lr)
{
    const int b = blockIdx.x;
    const int t = threadIdx.x;
    const int u = t >> 4;
    const int l = t & 15;
    const float* xp = X + ((size_t)b * Usz + u) * Dsz;
    const float* ap = alr + (size_t)u * Dsz;
    float s = 0.f;
    for (int d = l; d < Dsz; d += 16) s += xp[d] * ap[d];
    s += __shfl_down(s, 8, 16);
    s += __shfl_down(s, 4, 16);
    s += __shfl_down(s, 2, 16);
    s += __shfl_down(s, 1, 16);
    __shared__ float logits[16];
    if (l == 0) logits[u] = s;
    __syncthreads();
    if (t < 16) {
        const float T = temp[0];
        float m = -1e30f;
        #pragma unroll
        for (int i = 0; i < 16; i++) m = fmaxf(m, logits[i] / T);
        float sum = 0.f;
        #pragma unroll
        for (int i = 0; i < 16; i++) sum += expf(logits[i] / T - m);
        lr[(size_t)b * Usz + t] = expf(logits[t] / T - m) / sum;
    }
}

// ---- state: C = [X | state*sr] · [Win ; W] (K=1280), tanh/lr blend ----
// tile 32m x 64n, grid 1024 = 4 blocks/CU, double-buffered LDS (1 barrier/step),
// register prefetch 2 K-steps deep. id&15 == u -> same-u blocks cluster per XCD.
__global__ __launch_bounds__(256)
void state_mfma(const float* __restrict__ X, const float* __restrict__ state,
                const float* __restrict__ W, const float* __restrict__ Win,
                const float* __restrict__ bias, const float* __restrict__ sr,
                const float* __restrict__ lr, float* __restrict__ out0)
{
    const int id   = blockIdx.x;
    const int u    = id & 15;
    const int rest = id >> 4;        // 0..63
    const int nt   = rest & 15;
    const int mt   = rest >> 4;      // 0..3

    const int tid  = threadIdx.x;
    const int wave = tid >> 6, lane = tid & 63;
    const int l16  = lane & 15, kgl = lane >> 4;
    const int wrow = (wave & 1) * 16, wcol = (wave >> 1) * 32;

    // frag-cell layout per buffer: [blk][kg4][idx16][8 bf16]
    __shared__ __align__(16) unsigned short As[2][1024];   // 2 m-blks
    __shared__ __align__(16) unsigned short Bs[2][2048];   // 4 n-blks

    f32x4 acc[2] = {};

    const int  sm  = tid & 31;
    const int  skg = (tid >> 5) & 3;
    const bool doA = tid < 128;
    const int  sb_n = tid & 63, sb_kg = tid >> 6;
    const float sru = sr[u];

    const float* Af = X     + ((size_t)(mt * 32 + sm) * Usz + u) * Dsz + skg * 8;
    const float* Ae = state + ((size_t)(mt * 32 + sm) * Usz + u) * Nsz + skg * 8;
    const float* Bf = Win + (size_t)u * Dsz * Nsz + (size_t)(sb_kg * 8) * Nsz + nt * 64 + sb_n;
    const float* Be = W   + (size_t)u * Nsz * Nsz + (size_t)(sb_kg * 8) * Nsz + nt * 64 + sb_n;

    float areg[8], breg[8];
    auto loadA = [&](int kb) {
        if (!doA) return;
        const float* p = (kb < Dsz) ? (Af + kb) : (Ae + (kb - Dsz));
        const f32x4 v0 = *(const f32x4*)p;
        const f32x4 v1 = *(const f32x4*)(p + 4);
        #pragma unroll
        for (int i = 0; i < 4; i++) { areg[i] = v0[i]; areg[4 + i] = v1[i]; }
    };
    auto loadB = [&](int kb) {
        const float* p = (kb < Dsz) ? (Bf + (size_t)kb * Nsz)
                                    : (Be + (size_t)(kb - Dsz) * Nsz);
        #pragma unroll
        for (int j = 0; j < 8; j++) breg[j] = p[(size_t)j * Nsz];
    };

    const int wrA = ((sm >> 4) * 4 + skg) * 128 + (sm & 15) * 8;
    const int wrB = ((sb_n >> 4) * 4 + sb_kg) * 128 + (sb_n & 15) * 8;
    auto writeBuf = [&](int buf, int kb) {
        const float asc = (kb < Dsz) ? 1.f : sru;   // fold sr into echo A
        if (doA) *(bf16x8*)&As[buf][wrA] = pack8(areg, asc);
        *(bf16x8*)&Bs[buf][wrB] = pack8(breg, 1.f);
    };

    loadA(0); loadB(0);
    writeBuf(0, 0);
    loadA(32); loadB(32);
    __syncthreads();

    const int aoff  = (((wave & 1) * 4 + kgl) * 16 + l16) * 8;
    const int boff0 = ((((wcol >> 4) + 0) * 4 + kgl) * 16 + l16) * 8;
    const int boff1 = ((((wcol >> 4) + 1) * 4 + kgl) * 16 + l16) * 8;

    for (int step = 0; step < 40; ++step) {
        const int buf = step & 1;
        if (step + 1 < 40) writeBuf(buf ^ 1, (step + 1) * 32);
        if (step + 2 < 40) { loadA((step + 2) * 32); loadB((step + 2) * 32); }
        const bf16x8 afr = *(const bf16x8*)&As[buf][aoff];
        const bf16x8 b0  = *(const bf16x8*)&Bs[buf][boff0];
        const bf16x8 b1  = *(const bf16x8*)&Bs[buf][boff1];
        acc[0] = __builtin_amdgcn_mfma_f32_16x16x32_bf16(afr, b0, acc[0], 0, 0, 0);
        acc[1] = __builtin_amdgcn_mfma_f32_16x16x32_bf16(afr, b1, acc[1], 0, 0, 0);
        __syncthreads();
    }

    // C/D layout: col=lane&15, row=(lane>>4)*4+reg (HW-verified, matches R3)
    #pragma unroll
    for (int ni = 0; ni < 2; ni++) {
        const int gcol = nt * 64 + wcol + ni * 16 + l16;
        const float bi = bias[u * Nsz + gcol];
        #pragma unroll
        for (int rg = 0; rg < 4; rg++) {
            const int grow = mt * 32 + wrow + kgl * 4 + rg;
            const size_t idx = ((size_t)grow * Usz + u) * Nsz + gcol;
            const float th = tanhf(acc[ni][rg] + bi);
            const float sv = state[idx];
            const float lv = lr[grow * Usz + u];
            out0[idx] = (1.f - lv) * sv + lv * th;
        }
    }
}

// ---------------- out1 = ns · Wout, tile 16m x 64n, grid 512 ----------------
__global__ __launch_bounds__(256)
void out_mfma(const float* __restrict__ ns, const float* __restrict__ Wout,
              float* __restrict__ out1)
{
    const int id   = blockIdx.x;     // 512
    const int u    = id & 15;
    const int rest = id >> 4;        // 0..31
    const int ot   = rest & 3;
    const int mt   = rest >> 2;      // 0..7

    const int tid  = threadIdx.x;
    const int wave = tid >> 6, lane = tid & 63;
    const int l16  = lane & 15, kgl = lane >> 4;
    const int wcol = wave * 16;

    __shared__ __align__(16) unsigned short As[2][512];    // 1 m-blk
    __shared__ __align__(16) unsigned short Bs[2][2048];   // 4 n-blks

    f32x4 acc = {};

    const bool doA = tid < 64;
    const int  sm  = tid & 15, skg = (tid >> 4) & 3;
    const int  sb_n = tid & 63, sb_kg = tid >> 6;

    const float* Ap = ns + ((size_t)(mt * 16 + sm) * Usz + u) * Nsz + skg * 8;
    const float* Bp = Wout + (size_t)u * Nsz * Osz + (size_t)(sb_kg * 8) * Osz + ot * 64 + sb_n;

    float areg[8], breg[8];
    auto loadA = [&](int kb) {
        if (!doA) return;
        const f32x4 v0 = *(const f32x4*)(Ap + kb);
        const f32x4 v1 = *(const f32x4*)(Ap + kb + 4);
        #pragma unroll
        for (int i = 0; i < 4; i++) { areg[i] = v0[i]; areg[4 + i] = v1[i]; }
    };
    auto loadB = [&](int kb) {
        const float* p = Bp + (size_t)kb * Osz;
        #pragma unroll
        for (int j = 0; j < 8; j++) breg[j] = p[(size_t)j * Osz];
    };

    const int wrA = skg * 128 + sm * 8;
    const int wrB = ((sb_n >> 4) * 4 + sb_kg) * 128 + (sb_n & 15) * 8;
    auto writeBuf = [&](int buf) {
        if (doA) *(bf16x8*)&As[buf][wrA] = pack8(areg, 1.f);
        *(bf16x8*)&Bs[buf][wrB] = pack8(breg, 1.f);
    };

    loadA(0); loadB(0);
    writeBuf(0);
    loadA(32); loadB(32);
    __syncthreads();

    const int aoff = (kgl * 16 + l16) * 8;
    const int boff = ((wave * 4 + kgl) * 16 + l16) * 8;

    for (int step = 0; step < 32; ++step) {
        const int buf = step & 1;
        if (step + 1 < 32) writeBuf(buf ^ 1);
        if (step + 2 < 32) { loadA((step + 2) * 32); loadB((step + 2) * 32); }
        const bf16x8 afr = *(const bf16x8*)&As[buf][aoff];
        const bf16x8 bfr = *(const bf16x8*)&Bs[buf][boff];
        acc = __builtin_amdgcn_mfma_f32_16x16x32_bf16(afr, bfr, acc, 0, 0, 0);
        __syncthreads();
    }

    const int gcol = ot * 64 + wcol + l16;
    #pragma unroll
    for (int rg = 0; rg < 4; rg++) {
        const int grow = mt * 16 + kgl * 4 + rg;
        out1[((size_t)grow * Usz + u) * Osz + gcol] = acc[rg];
    }
}

extern "C" void kernel_launch(void* const* d_in, const int* in_sizes, int n_in,
                              void* d_out, int out_size, void* d_ws, size_t ws_size,
                              hipStream_t stream)
{
    (void)in_sizes; (void)n_in; (void)out_size; (void)ws_size;
    const float* X     = (const float*)d_in[0];
    const float* state = (const float*)d_in[1];
    const float* W     = (const float*)d_in[2];
    const float* Win   = (const float*)d_in[3];
    const float* bias  = (const float*)d_in[4];
    const float* Wout  = (const float*)d_in[5];
    const float* sr    = (const float*)d_in[6];
    const float* alr   = (const float*)d_in[7];
    const float* temp  = (const float*)d_in[8];

    float* out0 = (float*)d_out;                      // (B,U,N)
    float* out1 = out0 + (size_t)Bsz * Usz * Nsz;     // (B,U,O)
    float* lr   = (float*)d_ws;                       // (B,U) f32, 8 KB

    lr_kernel<<<Bsz, 256, 0, stream>>>(X, alr, temp, lr);
    state_mfma<<<1024, 256, 0, stream>>>(X, state, W, Win, bias, sr, lr, out0);
    out_mfma<<<512, 256, 0, stream>>>(out0, Wout, out1);
}

// Round 5
// 195.755 us; speedup vs baseline: 1.0409x; 1.0409x over previous
//
#include <hip/hip_runtime.h>
#include <math.h>

#define Bsz 128
#define Usz 16
#define Dsz 256
#define Nsz 1024
#define Osz 256

typedef __attribute__((ext_vector_type(4))) float f32x4;
typedef __attribute__((ext_vector_type(8))) short bf16x8;
typedef __attribute__((ext_vector_type(4))) unsigned int u32x4;

union cell_u { u32x4 u; bf16x8 b; };

__device__ __forceinline__ unsigned int fbits(float f) {
    union { float f; unsigned int u; } v; v.f = f; return v.u;
}
// pack two f32 -> (bf16(hi)<<16)|bf16(lo) by truncation: 1 v_perm_b32
__device__ __forceinline__ unsigned int pk(float lo, float hi) {
    return __builtin_amdgcn_perm(fbits(hi), fbits(lo), 0x07060302u);
}
__device__ __forceinline__ u32x4 pk8(const float* x) {
    u32x4 r;
    r[0] = pk(x[0], x[1]); r[1] = pk(x[2], x[3]);
    r[2] = pk(x[4], x[5]); r[3] = pk(x[6], x[7]);
    return r;
}

// ---------------- lr = softmax_u(X·alr / T) ----------------
__global__ __launch_bounds__(256)
void lr_kernel(const float* __restrict__ X, const float* __restrict__ alr,
               const float* __restrict__ temp, float* __restrict__ lr)
{
    const int b = blockIdx.x;
    const int t = threadIdx.x;
    const int u = t >> 4;
    const int l = t & 15;
    const float* xp = X + ((size_t)b * Usz + u) * Dsz;
    const float* ap = alr + (size_t)u * Dsz;
    float s = 0.f;
    for (int d = l; d < Dsz; d += 16) s += xp[d] * ap[d];
    s += __shfl_down(s, 8, 16);
    s += __shfl_down(s, 4, 16);
    s += __shfl_down(s, 2, 16);
    s += __shfl_down(s, 1, 16);
    __shared__ float logits[16];
    if (l == 0) logits[u] = s;
    __syncthreads();
    if (t < 16) {
        const float T = temp[0];
        float m = -1e30f;
        #pragma unroll
        for (int i = 0; i < 16; i++) m = fmaxf(m, logits[i] / T);
        float sum = 0.f;
        #pragma unroll
        for (int i = 0; i < 16; i++) sum += expf(logits[i] / T - m);
        lr[(size_t)b * Usz + t] = expf(logits[t] / T - m) / sum;
    }
}

// ---- state: C = [X | state*sr] · [Win ; W] (K=1280), tanh/lr blend ----
// tile 128m x 64n (m = whole batch -> W read exactly once, minimal demand),
// grid 256 = nt16 x u16 (1 block/CU; id%8==u%8 clusters same-u per XCD),
// 256 thr = 4 waves, wave = 128m x 16n (8 MFMA/step), K-step 32, dbuf LDS.
__global__ __launch_bounds__(256)
void state_mfma(const float* __restrict__ X, const float* __restrict__ state,
                const float* __restrict__ W, const float* __restrict__ Win,
                const float* __restrict__ bias, const float* __restrict__ sr,
                const float* __restrict__ lr, float* __restrict__ out0)
{
    const int id = blockIdx.x;
    const int u  = id & 15;
    const int nt = id >> 4;

    const int tid  = threadIdx.x;
    const int wave = tid >> 6, lane = tid & 63;
    const int l16  = lane & 15, kgl = lane >> 4;

    // frag cells: [blk][kg4][l16] of 8 bf16 (16B)
    __shared__ u32x4 As[2][512];   // 8 m-blks: 16 KB
    __shared__ u32x4 Bs[2][256];   // 4 n-blks:  8 KB

    f32x4 acc[8] = {};

    const int am = tid & 127, akg2 = tid >> 7;   // A: 16 k-contig els/thread
    const int bn = tid & 63,  bkg  = tid >> 6;   // B: 8 strided els/thread
    const float sru = sr[u];

    const float* Af = X     + ((size_t)am * Usz + u) * Dsz;
    const float* Ae = state + ((size_t)am * Usz + u) * Nsz;
    const float* Bf = Win + (size_t)u * Dsz * Nsz + nt * 64 + bn;
    const float* Be = W   + (size_t)u * Nsz * Nsz + nt * 64 + bn;

    float ar[16], br[8];

    auto loadA = [&](int kb) {
        const int kk = kb + akg2 * 16;
        const float* p = (kk < Dsz) ? (Af + kk) : (Ae + (kk - Dsz));
        #pragma unroll
        for (int q = 0; q < 4; q++) {
            const f32x4 v = *(const f32x4*)(p + q * 4);
            ar[q*4+0] = v[0]; ar[q*4+1] = v[1]; ar[q*4+2] = v[2]; ar[q*4+3] = v[3];
        }
    };
    auto loadB = [&](int kb) {
        const int kk = kb + bkg * 8;
        const float* p = (kk < Dsz) ? (Bf + (size_t)kk * Nsz)
                                    : (Be + (size_t)(kk - Dsz) * Nsz);
        #pragma unroll
        for (int j = 0; j < 8; j++) br[j] = p[(size_t)j * Nsz];
    };

    const int ca = (am >> 4) * 64 + (akg2 * 2) * 16 + (am & 15);
    const int cb = (bn >> 4) * 64 + bkg * 16 + (bn & 15);
    auto writeBuf = [&](int buf, int kb) {
        As[buf][ca]      = pk8(ar);
        As[buf][ca + 16] = pk8(ar + 8);
        const float sc = (kb + bkg * 8 >= Dsz) ? sru : 1.f;  // fold sr into W
        float t[8];
        #pragma unroll
        for (int j = 0; j < 8; j++) t[j] = br[j] * sc;
        Bs[buf][cb] = pk8(t);
    };

    loadA(0); loadB(0);
    writeBuf(0, 0);
    loadA(32); loadB(32);
    __syncthreads();

    for (int step = 0; step < 40; ++step) {
        const int buf = step & 1;
        if (step + 1 < 40) writeBuf(buf ^ 1, (step + 1) * 32);
        if (step + 2 < 40) { loadA((step + 2) * 32); loadB((step + 2) * 32); }
        cell_u bc; bc.u = Bs[buf][wave * 64 + kgl * 16 + l16];
        #pragma unroll
        for (int mi = 0; mi < 8; mi++) {
            cell_u ac; ac.u = As[buf][mi * 64 + kgl * 16 + l16];
            acc[mi] = __builtin_amdgcn_mfma_f32_16x16x32_bf16(ac.b, bc.b, acc[mi], 0, 0, 0);
        }
        __syncthreads();
    }

    // C/D layout: col=lane&15, row=(lane>>4)*4+reg (HW-verified, matches R3/R4)
    const int gcol = nt * 64 + wave * 16 + l16;
    const float bi = bias[u * Nsz + gcol];
    #pragma unroll
    for (int mi = 0; mi < 8; mi++) {
        #pragma unroll
        for (int rg = 0; rg < 4; rg++) {
            const int grow = mi * 16 + kgl * 4 + rg;
            const size_t idx = ((size_t)grow * Usz + u) * Nsz + gcol;
            const float th = tanhf(acc[mi][rg] + bi);
            const float sv = state[idx];
            const float lv = lr[grow * Usz + u];
            out0[idx] = (1.f - lv) * sv + lv * th;
        }
    }
}

// ---- out1 = ns · Wout: tile 128m x 64n, grid (64, KS); split-K via blockIdx.y ----
__global__ __launch_bounds__(256)
void out_mfma(const float* __restrict__ ns, const float* __restrict__ Wout,
              float* __restrict__ dst, int nsteps, int partial)
{
    const int id = blockIdx.x;       // 64 = u16 x ot4
    const int u  = id & 15;
    const int ot = id >> 4;
    const int ks = blockIdx.y;
    const int k0 = ks * nsteps * 32;

    const int tid  = threadIdx.x;
    const int wave = tid >> 6, lane = tid & 63;
    const int l16  = lane & 15, kgl = lane >> 4;

    __shared__ u32x4 As[2][512];
    __shared__ u32x4 Bs[2][256];

    f32x4 acc[8] = {};

    const int am = tid & 127, akg2 = tid >> 7;
    const int bn = tid & 63,  bkg  = tid >> 6;

    const float* Ap = ns + ((size_t)am * Usz + u) * Nsz + k0;
    const float* Bp = Wout + (size_t)u * Nsz * Osz + (size_t)k0 * Osz + ot * 64 + bn;

    float ar[16], br[8];
    auto loadA = [&](int kb) {
        const float* p = Ap + kb + akg2 * 16;
        #pragma unroll
        for (int q = 0; q < 4; q++) {
            const f32x4 v = *(const f32x4*)(p + q * 4);
            ar[q*4+0] = v[0]; ar[q*4+1] = v[1]; ar[q*4+2] = v[2]; ar[q*4+3] = v[3];
        }
    };
    auto loadB = [&](int kb) {
        const float* p = Bp + (size_t)(kb + bkg * 8) * Osz;
        #pragma unroll
        for (int j = 0; j < 8; j++) br[j] = p[(size_t)j * Osz];
    };

    const int ca = (am >> 4) * 64 + (akg2 * 2) * 16 + (am & 15);
    const int cb = (bn >> 4) * 64 + bkg * 16 + (bn & 15);
    auto writeBuf = [&](int buf) {
        As[buf][ca]      = pk8(ar);
        As[buf][ca + 16] = pk8(ar + 8);
        Bs[buf][cb] = pk8(br);
    };

    loadA(0); loadB(0);
    writeBuf(0);
    loadA(32); loadB(32);
    __syncthreads();

    for (int step = 0; step < nsteps; ++step) {
        const int buf = step & 1;
        if (step + 1 < nsteps) writeBuf(buf ^ 1);
        if (step + 2 < nsteps) { loadA((step + 2) * 32); loadB((step + 2) * 32); }
        cell_u bc; bc.u = Bs[buf][wave * 64 + kgl * 16 + l16];
        #pragma unroll
        for (int mi = 0; mi < 8; mi++) {
            cell_u ac; ac.u = As[buf][mi * 64 + kgl * 16 + l16];
            acc[mi] = __builtin_amdgcn_mfma_f32_16x16x32_bf16(ac.b, bc.b, acc[mi], 0, 0, 0);
        }
        __syncthreads();
    }

    const int c16 = wave * 16 + l16;
    #pragma unroll
    for (int mi = 0; mi < 8; mi++) {
        #pragma unroll
        for (int rg = 0; rg < 4; rg++) {
            const int grow = mi * 16 + kgl * 4 + rg;
            if (partial)
                dst[((((size_t)ks * 16 + u) * 4 + ot) * 128 + grow) * 64 + c16] = acc[mi][rg];
            else
                dst[((size_t)grow * Usz + u) * Osz + ot * 64 + c16] = acc[mi][rg];
        }
    }
}

// ---- sum 4 split-K partials -> out1 ----
__global__ __launch_bounds__(256)
void reduce_out(const float* __restrict__ part, float* __restrict__ out1)
{
    const int i = blockIdx.x * 256 + threadIdx.x;    // 0..131071
    const int base = i * 4;                          // flat out1 idx, 4-contig
    const int m   = base >> 12;
    const int u   = (base >> 8) & 15;
    const int oc  = base & 255;
    const int ot  = oc >> 6;
    const int col = oc & 63;
    const size_t pb = (((size_t)u * 4 + ot) * 128 + m) * 64 + col;
    const size_t stride = (size_t)16 * 4 * 128 * 64;   // floats per ks slab
    f32x4 s = *(const f32x4*)(part + pb);
    #pragma unroll
    for (int ks = 1; ks < 4; ks++) s += *(const f32x4*)(part + pb + ks * stride);
    *(f32x4*)(out1 + base) = s;
}

extern "C" void kernel_launch(void* const* d_in, const int* in_sizes, int n_in,
                              void* d_out, int out_size, void* d_ws, size_t ws_size,
                              hipStream_t stream)
{
    (void)in_sizes; (void)n_in; (void)out_size;
    const float* X     = (const float*)d_in[0];
    const float* state = (const float*)d_in[1];
    const float* W     = (const float*)d_in[2];
    const float* Win   = (const float*)d_in[3];
    const float* bias  = (const float*)d_in[4];
    const float* Wout  = (const float*)d_in[5];
    const float* sr    = (const float*)d_in[6];
    const float* alr   = (const float*)d_in[7];
    const float* temp  = (const float*)d_in[8];

    float* out0 = (float*)d_out;                      // (B,U,N)
    float* out1 = out0 + (size_t)Bsz * Usz * Nsz;     // (B,U,O)
    float* lr   = (float*)d_ws;                       // 8 KB

    const size_t part_off = 8192;
    const size_t part_bytes = (size_t)4 * 16 * 4 * 128 * 64 * 4;   // 8 MiB

    lr_kernel<<<Bsz, 256, 0, stream>>>(X, alr, temp, lr);
    state_mfma<<<256, 256, 0, stream>>>(X, state, W, Win, bias, sr, lr, out0);

    if (ws_size >= part_off + part_bytes) {
        float* part = (float*)((char*)d_ws + part_off);
        out_mfma<<<dim3(64, 4), 256, 0, stream>>>(out0, Wout, part, 8, 1);
        reduce_out<<<512, 256, 0, stream>>>(part, out1);
    } else {
        out_mfma<<<dim3(64, 1), 256, 0, stream>>>(out0, Wout, out1, 32, 0);
    }
}